// Round 6
// baseline (1416.958 us; speedup 1.0000x reference)
//
#include <hip/hip_runtime.h>
#include <hip/hip_bf16.h>

// GCN: x=emb[ids]; x1=relu(GCNConv(x,W1,b1)); y=Ahat@x1; out[g]=b2+(mean_g y)@W2
// Ahat = sym-normalized adjacency with self loops (norm = dinv[src]*dinv[dst]).
//
// Restructuring:
//  - conv1: rank-17 input -> h1=(emb@W1)[type]; neighbor sum factors through
//    17 type bins C[i][t] (edge-parallel atomics), then dense 17-term FMA.
//  - conv2 commutes with @W2 and mean-pool -> only poolY[64][128] is needed.
//  - R5/R6: NO CSR. conv2 edge-parallel, per-block LDS accumulator (32 KB).
//    R6 fix of R5's 12x regression (one outstanding gather per wave):
//    fixed-trip 64-item chunks padded with w=0, 8-wide unrolled gathers
//    (8 outstanding 256 B loads/wave), and NO global atomics: each block
//    streams its accumulator to poolPart[block]; k_out reduces partials.
//  - R2: x1 stored bf16; lane holds features {lane, lane+64}.

#define DDIM 128
#define CPAD 20     // C row stride (17 used, padded for 16B-aligned float4 reads)
#define NPART 512   // conv2e grid = NPART blocks, each writes one 32 KB partial
typedef unsigned int uint;

__device__ __forceinline__ float bflo(uint v) { return __uint_as_float(v << 16); }
__device__ __forceinline__ float bfhi(uint v) { return __uint_as_float(v & 0xffff0000u); }
__device__ __forceinline__ uint packbf(float x, float y) {  // RNE round both
    uint ux = __float_as_uint(x), uy = __float_as_uint(y);
    ux = (ux + 0x7fff + ((ux >> 16) & 1)) >> 16;
    uy = (uy + 0x7fff + ((uy >> 16) & 1)) & 0xffff0000u;
    return ux | uy;
}

__global__ void k_deg(const int* __restrict__ dst, int* __restrict__ deg, int E) {
    int i = blockIdx.x * blockDim.x + threadIdx.x;
    int stride = gridDim.x * blockDim.x;
    for (int e = i; e < E; e += stride) atomicAdd(&deg[dst[e]], 1);
}

// nd[i] = {dinv_i, type_i bits}; deg is edge-only indegree, +1 self loop.
__global__ void k_pack(const int* __restrict__ deg, const int* __restrict__ ids,
                       float2* __restrict__ nd, int N) {
    int i = blockIdx.x * blockDim.x + threadIdx.x;
    if (i < N) {
        float dinv = rsqrtf((float)(deg[i] + 1));
        nd[i] = make_float2(dinv, __int_as_float(ids[i]));
    }
}

// C[dst][type_src] += dinv_src  (edge-parallel, scalar fp32 atomics over 8 MB)
__global__ void k_bin(const int* __restrict__ src, const int* __restrict__ dst,
                      const float2* __restrict__ nd, float* __restrict__ C, int E) {
    int i = blockIdx.x * blockDim.x + threadIdx.x;
    int stride = gridDim.x * blockDim.x;
    for (int e = i; e < E; e += stride) {
        int s = src[e];
        int d = dst[e];
        float2 ns = nd[s];
        atomicAdd(&C[d * CPAD + __float_as_int(ns.y)], ns.x);
    }
}

// t1 = emb @ W1  (17 x 128)
__global__ void k_t1(const float* __restrict__ emb, const float* __restrict__ W1,
                     float* __restrict__ t1) {
    int t = blockIdx.x, f = threadIdx.x;
    float acc = 0.f;
    for (int k = 0; k < DDIM; k++) acc += emb[t * DDIM + k] * W1[k * DDIM + f];
    t1[t * DDIM + f] = acc;
}

// x1[i] = relu(b1 + dinv_i*(sum_t C[i][t]*t1[t] + dinv_i*t1[ti]))  -> bf16x2
// Lane holds features {lane, lane+64} packed as {lo, hi}. 4 waves/block.
__global__ void __launch_bounds__(256) k_x1(
        const float2* __restrict__ nd, const float* __restrict__ C,
        const float* __restrict__ t1, const float* __restrict__ b1,
        uint* __restrict__ x1u, int N) {
    int lane = threadIdx.x & 63, wave = threadIdx.x >> 6;
    int i = blockIdx.x * 4 + wave;
    if (i >= N) return;
    float2 ndi = nd[i];
    float dinv_i = ndi.x;
    int ti = __float_as_int(ndi.y);
    const float4* Cv = (const float4*)(C + i * CPAD);
    float4 c0 = Cv[0], c1 = Cv[1], c2 = Cv[2], c3 = Cv[3];
    float c16 = C[i * CPAD + 16];
    float cc[17] = {c0.x, c0.y, c0.z, c0.w, c1.x, c1.y, c1.z, c1.w,
                    c2.x, c2.y, c2.z, c2.w, c3.x, c3.y, c3.z, c3.w, c16};
    float ax = dinv_i * t1[ti * DDIM + lane];          // self loop
    float ay = dinv_i * t1[ti * DDIM + 64 + lane];
#pragma unroll
    for (int t = 0; t < 17; t++) {
        ax += cc[t] * t1[t * DDIM + lane];
        ay += cc[t] * t1[t * DDIM + 64 + lane];
    }
    float vx = b1[lane]      + dinv_i * ax;
    float vy = b1[64 + lane] + dinv_i * ay;
    vx = vx > 0.f ? vx : 0.f;
    vy = vy > 0.f ? vy : 0.f;
    x1u[i * 64 + lane] = packbf(vx, vy);
}

// Edge-parallel conv2+pool: item space = E edges + N self loops.
// Per block: private fp32 acc[64][128] in LDS. Each wave stages 64 items
// (padded with w=0), then processes them 8 at a time: 8 independent 256 B
// row gathers in flight, then 16 stride-1 ds_add_f32 (2-way, conflict-free).
// Flush: plain streamed store to poolPart[block] (no global atomics).
__global__ void __launch_bounds__(256) k_conv2e(
        const int* __restrict__ src, const int* __restrict__ dst,
        const int* __restrict__ batch, const float2* __restrict__ nd,
        const uint* __restrict__ x1u, float* __restrict__ poolPart,
        int E, int N) {
    __shared__ float acc[64 * DDIM];       // 32 KB graph accumulator
    __shared__ float4 meta[4][64];         // per-wave staged items
    int t = threadIdx.x;
    for (int k = t; k < 64 * DDIM; k += 256) acc[k] = 0.f;
    __syncthreads();

    int lane = t & 63, wave = t >> 6;
    int M = E + N;
    int stride = gridDim.x * 4 * 64;
    for (int base = (blockIdx.x * 4 + wave) * 64; base < M; base += stride) {
        int item = base + lane;
        int s = 0, g = 0; float w = 0.f;
        if (item < E) {                    // real edge
            s = src[item];
            int d = dst[item];
            w = nd[s].x * nd[d].x;
            g = batch[d];
        } else if (item < M) {             // self loop of node i
            int i = item - E;
            s = i;
            float di = nd[i].x;
            w = di * di;
            g = batch[i];
        }                                  // padded: w=0 -> adds 0 to acc[0..]
        meta[wave][lane] = make_float4(__int_as_float(s), w, __int_as_float(g), 0.f);
#pragma unroll
        for (int jj = 0; jj < 64; jj += 8) {
            float4 m0 = meta[wave][jj + 0], m1 = meta[wave][jj + 1];
            float4 m2 = meta[wave][jj + 2], m3 = meta[wave][jj + 3];
            float4 m4 = meta[wave][jj + 4], m5 = meta[wave][jj + 5];
            float4 m6 = meta[wave][jj + 6], m7 = meta[wave][jj + 7];
            uint v0 = x1u[__float_as_int(m0.x) * 64 + lane];
            uint v1 = x1u[__float_as_int(m1.x) * 64 + lane];
            uint v2 = x1u[__float_as_int(m2.x) * 64 + lane];
            uint v3 = x1u[__float_as_int(m3.x) * 64 + lane];
            uint v4 = x1u[__float_as_int(m4.x) * 64 + lane];
            uint v5 = x1u[__float_as_int(m5.x) * 64 + lane];
            uint v6 = x1u[__float_as_int(m6.x) * 64 + lane];
            uint v7 = x1u[__float_as_int(m7.x) * 64 + lane];
            atomicAdd(&acc[__float_as_int(m0.z) * DDIM + lane],      m0.y * bflo(v0));
            atomicAdd(&acc[__float_as_int(m0.z) * DDIM + 64 + lane], m0.y * bfhi(v0));
            atomicAdd(&acc[__float_as_int(m1.z) * DDIM + lane],      m1.y * bflo(v1));
            atomicAdd(&acc[__float_as_int(m1.z) * DDIM + 64 + lane], m1.y * bfhi(v1));
            atomicAdd(&acc[__float_as_int(m2.z) * DDIM + lane],      m2.y * bflo(v2));
            atomicAdd(&acc[__float_as_int(m2.z) * DDIM + 64 + lane], m2.y * bfhi(v2));
            atomicAdd(&acc[__float_as_int(m3.z) * DDIM + lane],      m3.y * bflo(v3));
            atomicAdd(&acc[__float_as_int(m3.z) * DDIM + 64 + lane], m3.y * bfhi(v3));
            atomicAdd(&acc[__float_as_int(m4.z) * DDIM + lane],      m4.y * bflo(v4));
            atomicAdd(&acc[__float_as_int(m4.z) * DDIM + 64 + lane], m4.y * bfhi(v4));
            atomicAdd(&acc[__float_as_int(m5.z) * DDIM + lane],      m5.y * bflo(v5));
            atomicAdd(&acc[__float_as_int(m5.z) * DDIM + 64 + lane], m5.y * bfhi(v5));
            atomicAdd(&acc[__float_as_int(m6.z) * DDIM + lane],      m6.y * bflo(v6));
            atomicAdd(&acc[__float_as_int(m6.z) * DDIM + 64 + lane], m6.y * bfhi(v6));
            atomicAdd(&acc[__float_as_int(m7.z) * DDIM + lane],      m7.y * bflo(v7));
            atomicAdd(&acc[__float_as_int(m7.z) * DDIM + 64 + lane], m7.y * bfhi(v7));
        }
    }
    __syncthreads();
    float* myPart = poolPart + (size_t)blockIdx.x * 64 * DDIM;
    for (int k = t; k < 64 * DDIM; k += 256) myPart[k] = acc[k];
}

// out[g] = b2 + (sum_p poolPart[p][g] / cnt[g]) @ W2 ; cnt==0 -> 0.
// cnt[g] via binary search on sorted batch (fused, no separate kernel).
__global__ void __launch_bounds__(128) k_out(
        const float* __restrict__ poolPart, const int* __restrict__ batch,
        const float* __restrict__ W2, const float* __restrict__ b2,
        float* __restrict__ out, int N) {
    __shared__ float py[DDIM];
    __shared__ int cs;
    int g = blockIdx.x, f = threadIdx.x;
    float s = 0.f;
    for (int p = 0; p < NPART; p++) s += poolPart[(size_t)p * 64 * DDIM + g * DDIM + f];
    py[f] = s;
    if (f == 0) {
        auto lb = [&](int key) {
            int lo = 0, hi = N;
            while (lo < hi) {
                int mid = (lo + hi) >> 1;
                if (batch[mid] < key) lo = mid + 1; else hi = mid;
            }
            return lo;
        };
        cs = lb(g + 1) - lb(g);
    }
    __syncthreads();
    float acc = 0.f;
    for (int k = 0; k < DDIM; k++) acc += py[k] * W2[k * DDIM + f];
    int c = cs;
    out[g * DDIM + f] = (c > 0) ? (b2[f] + acc / (float)c) : 0.f;
}

extern "C" void kernel_launch(void* const* d_in, const int* in_sizes, int n_in,
                              void* d_out, int out_size, void* d_ws, size_t ws_size,
                              hipStream_t stream) {
    const int* node_ids = (const int*)d_in[0];
    const int* edge_index = (const int*)d_in[1];
    const int* batch = (const int*)d_in[2];
    const float* emb = (const float*)d_in[4];
    const float* W1 = (const float*)d_in[5];
    const float* b1 = (const float*)d_in[6];
    const float* W2 = (const float*)d_in[7];
    const float* b2 = (const float*)d_in[8];
    float* out = (float*)d_out;

    const int N = in_sizes[0];
    const int E = in_sizes[1] / 2;
    const int* src = edge_index;
    const int* dst = edge_index + E;

    char* ws = (char*)d_ws;
    size_t off = 0;
    auto carve = [&](size_t bytes) { char* p = ws + off; off = (off + bytes + 255) & ~size_t(255); return p; };
    uint*   x1u      = (uint*)carve((size_t)N * 64 * 4);       // bf16x2 packed
    float*  C        = (float*)carve((size_t)N * CPAD * 4);    // type bins
    float2* nd       = (float2*)carve((size_t)N * 8);
    int*    deg      = (int*)carve((size_t)N * 4);
    float*  t1       = (float*)carve(17 * DDIM * 4);
    float*  poolPart = (float*)carve((size_t)NPART * 64 * DDIM * 4);  // 16 MB

    hipMemsetAsync(deg, 0, (size_t)N * 4, stream);
    hipMemsetAsync(C,   0, (size_t)N * CPAD * 4, stream);

    k_deg<<<2048, 256, 0, stream>>>(dst, deg, E);
    k_pack<<<(N + 255) / 256, 256, 0, stream>>>(deg, node_ids, nd, N);
    k_bin<<<2048, 256, 0, stream>>>(src, dst, nd, C, E);

    k_t1<<<17, DDIM, 0, stream>>>(emb, W1, t1);
    k_x1<<<(N + 3) / 4, 256, 0, stream>>>(nd, C, t1, b1, x1u, N);
    k_conv2e<<<NPART, 256, 0, stream>>>(src, dst, batch, nd, x1u, poolPart, E, N);
    k_out<<<64, 128, 0, stream>>>(poolPart, batch, W2, b2, out, N);
}

// Round 7
// 402.596 us; speedup vs baseline: 3.5196x; 3.5196x over previous
//
#include <hip/hip_runtime.h>
#include <hip/hip_bf16.h>

// GCN: x=emb[ids]; x1=relu(GCNConv(x,W1,b1)); y=Ahat@x1; out[g]=b2+(mean_g y)@W2
//
// Structure (R7):
//  - conv1: rank-17 input -> t1=(emb@W1); per-node 17 type bins C (edge atomics)
//    then dense 17-term FMA -> x1 (bf16x2, lane holds feats {lane, lane+64}).
//  - conv2+pool fully edge-parallel: poolY[g] = sum over items (E edges + N
//    self loops) of w*x1[src], w = dinv_s*dinv_d (dinv_i^2 for self loops),
//    g = batch[dst]. Items partitioned BY GRAPH (deterministic two-pass,
//    per-block bases, no global cursors), then per-graph blocks accumulate in
//    REGISTERS (R5/R6 post-mortem: same-address LDS atomic RMW serializes at
//    ~150 cyc/op per CU -> 1120 us; register FMA removes it).

#define DDIM 128
#define CPAD 20      // C row stride (17 used; 80 B keeps float4 alignment)
#define GMAX 64
#define NPB  512     // partition blocks (fixed item ranges)
#define SLICES 32    // conv2 blocks per graph
typedef unsigned int uint;

__device__ __forceinline__ float bflo(uint v) { return __uint_as_float(v << 16); }
__device__ __forceinline__ float bfhi(uint v) { return __uint_as_float(v & 0xffff0000u); }
__device__ __forceinline__ uint packbf(float x, float y) {  // RNE round both
    uint ux = __float_as_uint(x), uy = __float_as_uint(y);
    ux = (ux + 0x7fff + ((ux >> 16) & 1)) >> 16;
    uy = (uy + 0x7fff + ((uy >> 16) & 1)) & 0xffff0000u;
    return ux | uy;
}

// Pass 1: deg atomics + per-block per-graph item histogram (items = E edges + N nodes)
__global__ void __launch_bounds__(256) k_p1(
        const int* __restrict__ dst, const int* __restrict__ batch,
        int* __restrict__ deg, int* __restrict__ blockHist, int E, int M) {
    __shared__ int h[4][GMAX];
    int t = threadIdx.x, wave = t >> 6;
    if ((t & 63) < GMAX) h[wave][t & 63] = 0;
    __syncthreads();
    int per = (M + NPB - 1) / NPB;
    int lo = blockIdx.x * per;
    int hi = lo + per; if (hi > M) hi = M;
    for (int item = lo + t; item < hi; item += 256) {
        int g;
        if (item < E) {
            int d = dst[item];
            atomicAdd(&deg[d], 1);
            g = batch[d];
        } else {
            g = batch[item - E];
        }
        atomicAdd(&h[wave][g], 1);
    }
    __syncthreads();
    if (t < GMAX)
        blockHist[blockIdx.x * GMAX + t] = h[0][t] + h[1][t] + h[2][t] + h[3][t];
}

// Scan: totals per graph -> gStart[65]; exclusive over blocks -> blockBase[NPB][64]
__global__ void k_scanB(const int* __restrict__ blockHist,
                        int* __restrict__ blockBase, int* __restrict__ gStart) {
    __shared__ int tot[GMAX];
    int t = threadIdx.x;
    if (t < GMAX) {
        int s = 0;
        for (int b = 0; b < NPB; b++) s += blockHist[b * GMAX + t];
        tot[t] = s;
    }
    __syncthreads();
    if (t == 0) {
        int run = 0;
        for (int g = 0; g < GMAX; g++) { gStart[g] = run; run += tot[g]; }
        gStart[GMAX] = run;
    }
    __syncthreads();
    if (t < GMAX) {
        int run = gStart[t];
        for (int b = 0; b < NPB; b++) {
            blockBase[b * GMAX + t] = run;
            run += blockHist[b * GMAX + t];
        }
    }
}

// nd[i] = {dinv_i, type_i bits}
__global__ void k_pack(const int* __restrict__ deg, const int* __restrict__ ids,
                       float2* __restrict__ nd, int N) {
    int i = blockIdx.x * blockDim.x + threadIdx.x;
    if (i < N) {
        float dinv = rsqrtf((float)(deg[i] + 1));
        nd[i] = make_float2(dinv, __int_as_float(ids[i]));
    }
}

// C[dst][type_src] += dinv_src
__global__ void k_bin(const int* __restrict__ src, const int* __restrict__ dst,
                      const float2* __restrict__ nd, float* __restrict__ C, int E) {
    int i = blockIdx.x * blockDim.x + threadIdx.x;
    int stride = gridDim.x * blockDim.x;
    for (int e = i; e < E; e += stride) {
        int s = src[e];
        int d = dst[e];
        float2 ns = nd[s];
        atomicAdd(&C[d * CPAD + __float_as_int(ns.y)], ns.x);
    }
}

// Pass 2: deterministic partition of items into parts[] = {src bits, w} by graph
__global__ void __launch_bounds__(256) k_part(
        const int* __restrict__ src, const int* __restrict__ dst,
        const int* __restrict__ batch, const float2* __restrict__ nd,
        const int* __restrict__ blockBase, float2* __restrict__ parts,
        int E, int M) {
    __shared__ int rk[GMAX];
    __shared__ int base[GMAX];
    int t = threadIdx.x, b = blockIdx.x;
    if (t < GMAX) base[t] = blockBase[b * GMAX + t];
    int per = (M + NPB - 1) / NPB;
    int lo = b * per;
    int hi = lo + per; if (hi > M) hi = M;
    for (int cb = lo; cb < hi; cb += 1024) {
        if (t < GMAX) rk[t] = 0;
        __syncthreads();
        int s_[4], g_[4], r_[4]; float w_[4]; bool v_[4];
#pragma unroll
        for (int q = 0; q < 4; q++) {
            int item = cb + q * 256 + t;
            v_[q] = item < hi;
            s_[q] = 0; w_[q] = 0.f; g_[q] = 0; r_[q] = 0;
            if (v_[q]) {
                if (item < E) {
                    int s = src[item], d = dst[item];
                    s_[q] = s;
                    w_[q] = nd[s].x * nd[d].x;
                    g_[q] = batch[d];
                } else {
                    int i = item - E;
                    float di = nd[i].x;
                    s_[q] = i;
                    w_[q] = di * di;
                    g_[q] = batch[i];
                }
                r_[q] = atomicAdd(&rk[g_[q]], 1);
            }
        }
        __syncthreads();
#pragma unroll
        for (int q = 0; q < 4; q++)
            if (v_[q]) parts[base[g_[q]] + r_[q]] =
                make_float2(__int_as_float(s_[q]), w_[q]);
        __syncthreads();
        if (t < GMAX) base[t] += rk[t];
        __syncthreads();
    }
}

// t1 = emb @ W1  (17 x 128)
__global__ void k_t1(const float* __restrict__ emb, const float* __restrict__ W1,
                     float* __restrict__ t1) {
    int t = blockIdx.x, f = threadIdx.x;
    float acc = 0.f;
    for (int k = 0; k < DDIM; k++) acc += emb[t * DDIM + k] * W1[k * DDIM + f];
    t1[t * DDIM + f] = acc;
}

// x1[i] = relu(b1 + dinv_i*(sum_t C[i][t]*t1[t] + dinv_i*t1[ti]))  -> bf16x2
__global__ void __launch_bounds__(256) k_x1(
        const float2* __restrict__ nd, const float* __restrict__ C,
        const float* __restrict__ t1, const float* __restrict__ b1,
        uint* __restrict__ x1u, int N) {
    int lane = threadIdx.x & 63, wave = threadIdx.x >> 6;
    int i = blockIdx.x * 4 + wave;
    if (i >= N) return;
    float2 ndi = nd[i];
    float dinv_i = ndi.x;
    int ti = __float_as_int(ndi.y);
    const float4* Cv = (const float4*)(C + i * CPAD);
    float4 c0 = Cv[0], c1 = Cv[1], c2 = Cv[2], c3 = Cv[3];
    float c16 = C[i * CPAD + 16];
    float cc[17] = {c0.x, c0.y, c0.z, c0.w, c1.x, c1.y, c1.z, c1.w,
                    c2.x, c2.y, c2.z, c2.w, c3.x, c3.y, c3.z, c3.w, c16};
    float ax = dinv_i * t1[ti * DDIM + lane];
    float ay = dinv_i * t1[ti * DDIM + 64 + lane];
#pragma unroll
    for (int t = 0; t < 17; t++) {
        ax += cc[t] * t1[t * DDIM + lane];
        ay += cc[t] * t1[t * DDIM + 64 + lane];
    }
    float vx = b1[lane]      + dinv_i * ax;
    float vy = b1[64 + lane] + dinv_i * ay;
    vx = vx > 0.f ? vx : 0.f;
    vy = vy > 0.f ? vy : 0.f;
    x1u[i * 64 + lane] = packbf(vx, vy);
}

// conv2+pool: block owns one (graph, slice); register accumulation; 8-wide gathers.
__global__ void __launch_bounds__(256) k_conv2g(
        const float2* __restrict__ parts, const int* __restrict__ gStart,
        const uint* __restrict__ x1u, float* __restrict__ poolY) {
    __shared__ float2 meta[4][64];
    __shared__ float red[4][DDIM];
    int t = threadIdx.x, lane = t & 63, wave = t >> 6;
    int g = blockIdx.x / SLICES, sl = blockIdx.x % SLICES;
    int a = gStart[g], bnd = gStart[g + 1];
    long long len = bnd - a;
    int s0 = a + (int)(len * sl / SLICES);
    int s1 = a + (int)(len * (sl + 1) / SLICES);
    float ax = 0.f, ay = 0.f;
    for (int cb = s0 + wave * 64; cb < s1; cb += 4 * 64) {
        int idx = cb + lane;
        float2 m = (idx < s1) ? parts[idx] : make_float2(__int_as_float(0), 0.f);
        meta[wave][lane] = m;   // within-wave LDS write->read (lgkm ordered)
#pragma unroll
        for (int jj = 0; jj < 64; jj += 8) {
            float2 m0 = meta[wave][jj + 0], m1 = meta[wave][jj + 1];
            float2 m2 = meta[wave][jj + 2], m3 = meta[wave][jj + 3];
            float2 m4 = meta[wave][jj + 4], m5 = meta[wave][jj + 5];
            float2 m6 = meta[wave][jj + 6], m7 = meta[wave][jj + 7];
            uint v0 = x1u[__float_as_int(m0.x) * 64 + lane];
            uint v1 = x1u[__float_as_int(m1.x) * 64 + lane];
            uint v2 = x1u[__float_as_int(m2.x) * 64 + lane];
            uint v3 = x1u[__float_as_int(m3.x) * 64 + lane];
            uint v4 = x1u[__float_as_int(m4.x) * 64 + lane];
            uint v5 = x1u[__float_as_int(m5.x) * 64 + lane];
            uint v6 = x1u[__float_as_int(m6.x) * 64 + lane];
            uint v7 = x1u[__float_as_int(m7.x) * 64 + lane];
            ax += m0.y * bflo(v0) + m1.y * bflo(v1) + m2.y * bflo(v2) + m3.y * bflo(v3)
                + m4.y * bflo(v4) + m5.y * bflo(v5) + m6.y * bflo(v6) + m7.y * bflo(v7);
            ay += m0.y * bfhi(v0) + m1.y * bfhi(v1) + m2.y * bfhi(v2) + m3.y * bfhi(v3)
                + m4.y * bfhi(v4) + m5.y * bfhi(v5) + m6.y * bfhi(v6) + m7.y * bfhi(v7);
        }
    }
    red[wave][lane] = ax;
    red[wave][64 + lane] = ay;
    __syncthreads();
    if (wave == 0) {
        float vx = red[0][lane] + red[1][lane] + red[2][lane] + red[3][lane];
        float vy = red[0][64 + lane] + red[1][64 + lane] + red[2][64 + lane] + red[3][64 + lane];
        atomicAdd(&poolY[g * DDIM + lane], vx);
        atomicAdd(&poolY[g * DDIM + 64 + lane], vy);
    }
}

// out[g] = b2 + (poolY[g]/cnt[g]) @ W2 ; cnt via binary search on sorted batch
__global__ void __launch_bounds__(128) k_out(
        const float* __restrict__ poolY, const int* __restrict__ batch,
        const float* __restrict__ W2, const float* __restrict__ b2,
        float* __restrict__ out, int N) {
    __shared__ float py[DDIM];
    __shared__ int cs;
    int g = blockIdx.x, f = threadIdx.x;
    py[f] = poolY[g * DDIM + f];
    if (f == 0) {
        auto lb = [&](int key) {
            int lo = 0, hi = N;
            while (lo < hi) {
                int mid = (lo + hi) >> 1;
                if (batch[mid] < key) lo = mid + 1; else hi = mid;
            }
            return lo;
        };
        cs = lb(g + 1) - lb(g);
    }
    __syncthreads();
    float acc = 0.f;
    for (int k = 0; k < DDIM; k++) acc += py[k] * W2[k * DDIM + f];
    int c = cs;
    out[g * DDIM + f] = (c > 0) ? (b2[f] + acc / (float)c) : 0.f;
}

extern "C" void kernel_launch(void* const* d_in, const int* in_sizes, int n_in,
                              void* d_out, int out_size, void* d_ws, size_t ws_size,
                              hipStream_t stream) {
    const int* node_ids = (const int*)d_in[0];
    const int* edge_index = (const int*)d_in[1];
    const int* batch = (const int*)d_in[2];
    const float* emb = (const float*)d_in[4];
    const float* W1 = (const float*)d_in[5];
    const float* b1 = (const float*)d_in[6];
    const float* W2 = (const float*)d_in[7];
    const float* b2 = (const float*)d_in[8];
    float* out = (float*)d_out;

    const int N = in_sizes[0];
    const int E = in_sizes[1] / 2;
    const int M = E + N;
    const int* src = edge_index;
    const int* dst = edge_index + E;

    char* ws = (char*)d_ws;
    size_t off = 0;
    auto carve = [&](size_t bytes) { char* p = ws + off; off = (off + bytes + 255) & ~size_t(255); return p; };
    uint*   x1u       = (uint*)carve((size_t)N * 64 * 4);     // bf16x2 packed
    float2* parts     = (float2*)carve((size_t)M * 8);        // {src bits, w} by graph
    float*  C         = (float*)carve((size_t)N * CPAD * 4);  // type bins
    float2* nd        = (float2*)carve((size_t)N * 8);
    int*    deg       = (int*)carve((size_t)N * 4);
    int*    blockHist = (int*)carve((size_t)NPB * GMAX * 4);
    int*    blockBase = (int*)carve((size_t)NPB * GMAX * 4);
    int*    gStart    = (int*)carve((GMAX + 1) * 4);
    float*  t1        = (float*)carve(17 * DDIM * 4);
    float*  poolY     = (float*)carve((size_t)GMAX * DDIM * 4);

    hipMemsetAsync(deg,   0, (size_t)N * 4, stream);
    hipMemsetAsync(C,     0, (size_t)N * CPAD * 4, stream);
    hipMemsetAsync(poolY, 0, (size_t)GMAX * DDIM * 4, stream);

    k_p1<<<NPB, 256, 0, stream>>>(dst, batch, deg, blockHist, E, M);
    k_scanB<<<1, 256, 0, stream>>>(blockHist, blockBase, gStart);
    k_pack<<<(N + 255) / 256, 256, 0, stream>>>(deg, node_ids, nd, N);
    k_bin<<<2048, 256, 0, stream>>>(src, dst, nd, C, E);
    k_part<<<NPB, 256, 0, stream>>>(src, dst, batch, nd, blockBase, parts, E, M);

    k_t1<<<17, DDIM, 0, stream>>>(emb, W1, t1);
    k_x1<<<(N + 3) / 4, 256, 0, stream>>>(nd, C, t1, b1, x1u, N);
    k_conv2g<<<GMAX * SLICES, 256, 0, stream>>>(parts, gStart, x1u, poolY);
    k_out<<<GMAX, 128, 0, stream>>>(poolY, batch, W2, b2, out, N);
}

// Round 8
// 380.591 us; speedup vs baseline: 3.7230x; 1.0578x over previous
//
#include <hip/hip_runtime.h>
#include <hip/hip_bf16.h>

// GCN: x=emb[ids]; x1=relu(GCNConv(x,W1,b1)); y=Ahat@x1; out[g]=b2+(mean_g y)@W2
//
// Structure (R8):
//  - conv1: rank-17 input -> t1=(emb@W1); per-node 17 type bins C (edge atomics)
//    then dense 17-term FMA -> x1 (bf16x2, lane holds feats {lane, lane+64}).
//  - conv2+pool edge-parallel: items (E edges + N self loops) partitioned BY
//    GRAPH, per-graph blocks accumulate in REGISTERS (R6 post-mortem: LDS
//    atomic RMW with correlated addresses serializes; registers don't).
//  - R8: k_bin FUSED into k_part (one edge pass: partition + C atomics; the
//    fire-and-forget atomics overlap partition work). k_p1 4-wide batched
//    loads + caches g8[item]=batch[dst] so partbin reloads g coalesced.

#define DDIM 128
#define CPAD 20      // C row stride (17 used; 80 B keeps float4 alignment)
#define GMAX 64
#define NPB  512     // partition blocks (fixed item ranges)
#define SLICES 32    // conv2 blocks per graph
typedef unsigned int uint;
typedef unsigned char uchar;

__device__ __forceinline__ float bflo(uint v) { return __uint_as_float(v << 16); }
__device__ __forceinline__ float bfhi(uint v) { return __uint_as_float(v & 0xffff0000u); }
__device__ __forceinline__ uint packbf(float x, float y) {  // RNE round both
    uint ux = __float_as_uint(x), uy = __float_as_uint(y);
    ux = (ux + 0x7fff + ((ux >> 16) & 1)) >> 16;
    uy = (uy + 0x7fff + ((uy >> 16) & 1)) & 0xffff0000u;
    return ux | uy;
}

// Pass 1: deg atomics + per-block per-graph histogram + g8 cache.
// 4-wide batched loads for memory-level parallelism.
__global__ void __launch_bounds__(256) k_p1(
        const int* __restrict__ dst, const int* __restrict__ batch,
        int* __restrict__ deg, int* __restrict__ blockHist,
        uchar* __restrict__ g8, int E, int M) {
    __shared__ int h[4][GMAX];
    int t = threadIdx.x, wave = t >> 6;
    if ((t & 63) < GMAX) h[wave][t & 63] = 0;
    __syncthreads();
    int per = (M + NPB - 1) / NPB;
    int lo = blockIdx.x * per;
    int hi = lo + per; if (hi > M) hi = M;
    for (int cb = lo; cb < hi; cb += 1024) {
        int idx_[4]; bool v_[4], isE_[4];
#pragma unroll
        for (int q = 0; q < 4; q++) {
            int item = cb + q * 256 + t;
            v_[q] = item < hi;
            isE_[q] = item < E;
            idx_[q] = 0;
            if (v_[q]) idx_[q] = isE_[q] ? dst[item] : (item - E);
        }
#pragma unroll
        for (int q = 0; q < 4; q++) {
            if (v_[q]) {
                int g = batch[idx_[q]];              // 4 gathers in flight
                g8[cb + q * 256 + t] = (uchar)g;
                if (isE_[q]) atomicAdd(&deg[idx_[q]], 1);
                atomicAdd(&h[wave][g], 1);
            }
        }
    }
    __syncthreads();
    if (t < GMAX)
        blockHist[blockIdx.x * GMAX + t] = h[0][t] + h[1][t] + h[2][t] + h[3][t];
}

// Scan: totals per graph -> gStart[65]; exclusive over blocks -> blockBase[NPB][64]
__global__ void k_scanB(const int* __restrict__ blockHist,
                        int* __restrict__ blockBase, int* __restrict__ gStart) {
    __shared__ int tot[GMAX];
    int t = threadIdx.x;
    if (t < GMAX) {
        int s = 0;
        for (int b = 0; b < NPB; b++) s += blockHist[b * GMAX + t];
        tot[t] = s;
    }
    __syncthreads();
    if (t == 0) {
        int run = 0;
        for (int g = 0; g < GMAX; g++) { gStart[g] = run; run += tot[g]; }
        gStart[GMAX] = run;
    }
    __syncthreads();
    if (t < GMAX) {
        int run = gStart[t];
        for (int b = 0; b < NPB; b++) {
            blockBase[b * GMAX + t] = run;
            run += blockHist[b * GMAX + t];
        }
    }
}

// nd[i] = {dinv_i, type_i bits}
__global__ void k_pack(const int* __restrict__ deg, const int* __restrict__ ids,
                       float2* __restrict__ nd, int N) {
    int i = blockIdx.x * blockDim.x + threadIdx.x;
    if (i < N) {
        float dinv = rsqrtf((float)(deg[i] + 1));
        nd[i] = make_float2(dinv, __int_as_float(ids[i]));
    }
}

// Pass 2 (fused R8): partition items into parts[]={src bits, w} by graph
// AND accumulate conv1 type bins C[d][type_s] += dinv_s for real edges.
__global__ void __launch_bounds__(256) k_partbin(
        const int* __restrict__ src, const int* __restrict__ dst,
        const uchar* __restrict__ g8, const float2* __restrict__ nd,
        const int* __restrict__ blockBase, float2* __restrict__ parts,
        float* __restrict__ C, int E, int M) {
    __shared__ int rk[GMAX];
    __shared__ int base[GMAX];
    int t = threadIdx.x, b = blockIdx.x;
    if (t < GMAX) base[t] = blockBase[b * GMAX + t];
    int per = (M + NPB - 1) / NPB;
    int lo = b * per;
    int hi = lo + per; if (hi > M) hi = M;
    for (int cb = lo; cb < hi; cb += 1024) {
        if (t < GMAX) rk[t] = 0;
        __syncthreads();
        int s_[4], g_[4], r_[4], d_[4]; float w_[4]; bool v_[4], isE_[4];
#pragma unroll
        for (int q = 0; q < 4; q++) {            // batched independent loads
            int item = cb + q * 256 + t;
            v_[q] = item < hi;
            isE_[q] = item < E;
            s_[q] = 0; d_[q] = 0; g_[q] = 0; r_[q] = 0; w_[q] = 0.f;
            if (v_[q]) {
                g_[q] = g8[item];
                if (isE_[q]) { s_[q] = src[item]; d_[q] = dst[item]; }
                else         { s_[q] = item - E;  d_[q] = item - E; }
            }
        }
#pragma unroll
        for (int q = 0; q < 4; q++) {            // gathers 8-wide in flight
            if (v_[q]) {
                float2 ns = nd[s_[q]];
                float dd = nd[d_[q]].x;
                w_[q] = ns.x * dd;
                if (isE_[q])                     // conv1 bin (fire-and-forget)
                    atomicAdd(&C[d_[q] * CPAD + __float_as_int(ns.y)], ns.x);
                r_[q] = atomicAdd(&rk[g_[q]], 1);
            }
        }
        __syncthreads();
#pragma unroll
        for (int q = 0; q < 4; q++)
            if (v_[q]) parts[base[g_[q]] + r_[q]] =
                make_float2(__int_as_float(s_[q]), w_[q]);
        __syncthreads();
        if (t < GMAX) base[t] += rk[t];
        __syncthreads();
    }
}

// t1 = emb @ W1  (17 x 128)
__global__ void k_t1(const float* __restrict__ emb, const float* __restrict__ W1,
                     float* __restrict__ t1) {
    int t = blockIdx.x, f = threadIdx.x;
    float acc = 0.f;
    for (int k = 0; k < DDIM; k++) acc += emb[t * DDIM + k] * W1[k * DDIM + f];
    t1[t * DDIM + f] = acc;
}

// x1[i] = relu(b1 + dinv_i*(sum_t C[i][t]*t1[t] + dinv_i*t1[ti]))  -> bf16x2
__global__ void __launch_bounds__(256) k_x1(
        const float2* __restrict__ nd, const float* __restrict__ C,
        const float* __restrict__ t1, const float* __restrict__ b1,
        uint* __restrict__ x1u, int N) {
    int lane = threadIdx.x & 63, wave = threadIdx.x >> 6;
    int i = blockIdx.x * 4 + wave;
    if (i >= N) return;
    float2 ndi = nd[i];
    float dinv_i = ndi.x;
    int ti = __float_as_int(ndi.y);
    const float4* Cv = (const float4*)(C + i * CPAD);
    float4 c0 = Cv[0], c1 = Cv[1], c2 = Cv[2], c3 = Cv[3];
    float c16 = C[i * CPAD + 16];
    float cc[17] = {c0.x, c0.y, c0.z, c0.w, c1.x, c1.y, c1.z, c1.w,
                    c2.x, c2.y, c2.z, c2.w, c3.x, c3.y, c3.z, c3.w, c16};
    float ax = dinv_i * t1[ti * DDIM + lane];
    float ay = dinv_i * t1[ti * DDIM + 64 + lane];
#pragma unroll
    for (int t = 0; t < 17; t++) {
        ax += cc[t] * t1[t * DDIM + lane];
        ay += cc[t] * t1[t * DDIM + 64 + lane];
    }
    float vx = b1[lane]      + dinv_i * ax;
    float vy = b1[64 + lane] + dinv_i * ay;
    vx = vx > 0.f ? vx : 0.f;
    vy = vy > 0.f ? vy : 0.f;
    x1u[i * 64 + lane] = packbf(vx, vy);
}

// conv2+pool: block owns one (graph, slice); register accumulation; 8-wide gathers.
__global__ void __launch_bounds__(256) k_conv2g(
        const float2* __restrict__ parts, const int* __restrict__ gStart,
        const uint* __restrict__ x1u, float* __restrict__ poolY) {
    __shared__ float2 meta[4][64];
    __shared__ float red[4][DDIM];
    int t = threadIdx.x, lane = t & 63, wave = t >> 6;
    int g = blockIdx.x / SLICES, sl = blockIdx.x % SLICES;
    int a = gStart[g], bnd = gStart[g + 1];
    long long len = bnd - a;
    int s0 = a + (int)(len * sl / SLICES);
    int s1 = a + (int)(len * (sl + 1) / SLICES);
    float ax = 0.f, ay = 0.f;
    for (int cb = s0 + wave * 64; cb < s1; cb += 4 * 64) {
        int idx = cb + lane;
        float2 m = (idx < s1) ? parts[idx] : make_float2(__int_as_float(0), 0.f);
        meta[wave][lane] = m;   // within-wave LDS write->read (lgkm ordered)
#pragma unroll
        for (int jj = 0; jj < 64; jj += 8) {
            float2 m0 = meta[wave][jj + 0], m1 = meta[wave][jj + 1];
            float2 m2 = meta[wave][jj + 2], m3 = meta[wave][jj + 3];
            float2 m4 = meta[wave][jj + 4], m5 = meta[wave][jj + 5];
            float2 m6 = meta[wave][jj + 6], m7 = meta[wave][jj + 7];
            uint v0 = x1u[__float_as_int(m0.x) * 64 + lane];
            uint v1 = x1u[__float_as_int(m1.x) * 64 + lane];
            uint v2 = x1u[__float_as_int(m2.x) * 64 + lane];
            uint v3 = x1u[__float_as_int(m3.x) * 64 + lane];
            uint v4 = x1u[__float_as_int(m4.x) * 64 + lane];
            uint v5 = x1u[__float_as_int(m5.x) * 64 + lane];
            uint v6 = x1u[__float_as_int(m6.x) * 64 + lane];
            uint v7 = x1u[__float_as_int(m7.x) * 64 + lane];
            ax += m0.y * bflo(v0) + m1.y * bflo(v1) + m2.y * bflo(v2) + m3.y * bflo(v3)
                + m4.y * bflo(v4) + m5.y * bflo(v5) + m6.y * bflo(v6) + m7.y * bflo(v7);
            ay += m0.y * bfhi(v0) + m1.y * bfhi(v1) + m2.y * bfhi(v2) + m3.y * bfhi(v3)
                + m4.y * bfhi(v4) + m5.y * bfhi(v5) + m6.y * bfhi(v6) + m7.y * bfhi(v7);
        }
    }
    red[wave][lane] = ax;
    red[wave][64 + lane] = ay;
    __syncthreads();
    if (wave == 0) {
        float vx = red[0][lane] + red[1][lane] + red[2][lane] + red[3][lane];
        float vy = red[0][64 + lane] + red[1][64 + lane] + red[2][64 + lane] + red[3][64 + lane];
        atomicAdd(&poolY[g * DDIM + lane], vx);
        atomicAdd(&poolY[g * DDIM + 64 + lane], vy);
    }
}

// out[g] = b2 + (poolY[g]/cnt[g]) @ W2 ; cnt via binary search on sorted batch
__global__ void __launch_bounds__(128) k_out(
        const float* __restrict__ poolY, const int* __restrict__ batch,
        const float* __restrict__ W2, const float* __restrict__ b2,
        float* __restrict__ out, int N) {
    __shared__ float py[DDIM];
    __shared__ int cs;
    int g = blockIdx.x, f = threadIdx.x;
    py[f] = poolY[g * DDIM + f];
    if (f == 0) {
        auto lb = [&](int key) {
            int lo = 0, hi = N;
            while (lo < hi) {
                int mid = (lo + hi) >> 1;
                if (batch[mid] < key) lo = mid + 1; else hi = mid;
            }
            return lo;
        };
        cs = lb(g + 1) - lb(g);
    }
    __syncthreads();
    float acc = 0.f;
    for (int k = 0; k < DDIM; k++) acc += py[k] * W2[k * DDIM + f];
    int c = cs;
    out[g * DDIM + f] = (c > 0) ? (b2[f] + acc / (float)c) : 0.f;
}

extern "C" void kernel_launch(void* const* d_in, const int* in_sizes, int n_in,
                              void* d_out, int out_size, void* d_ws, size_t ws_size,
                              hipStream_t stream) {
    const int* node_ids = (const int*)d_in[0];
    const int* edge_index = (const int*)d_in[1];
    const int* batch = (const int*)d_in[2];
    const float* emb = (const float*)d_in[4];
    const float* W1 = (const float*)d_in[5];
    const float* b1 = (const float*)d_in[6];
    const float* W2 = (const float*)d_in[7];
    const float* b2 = (const float*)d_in[8];
    float* out = (float*)d_out;

    const int N = in_sizes[0];
    const int E = in_sizes[1] / 2;
    const int M = E + N;
    const int* src = edge_index;
    const int* dst = edge_index + E;

    char* ws = (char*)d_ws;
    size_t off = 0;
    auto carve = [&](size_t bytes) { char* p = ws + off; off = (off + bytes + 255) & ~size_t(255); return p; };
    uint*   x1u       = (uint*)carve((size_t)N * 64 * 4);     // bf16x2 packed
    float2* parts     = (float2*)carve((size_t)M * 8);        // {src bits, w} by graph
    float*  C         = (float*)carve((size_t)N * CPAD * 4);  // type bins
    float2* nd        = (float2*)carve((size_t)N * 8);
    int*    deg       = (int*)carve((size_t)N * 4);
    uchar*  g8        = (uchar*)carve((size_t)M);             // cached batch[dst]
    int*    blockHist = (int*)carve((size_t)NPB * GMAX * 4);
    int*    blockBase = (int*)carve((size_t)NPB * GMAX * 4);
    int*    gStart    = (int*)carve((GMAX + 1) * 4);
    float*  t1        = (float*)carve(17 * DDIM * 4);
    float*  poolY     = (float*)carve((size_t)GMAX * DDIM * 4);

    hipMemsetAsync(deg,   0, (size_t)N * 4, stream);
    hipMemsetAsync(C,     0, (size_t)N * CPAD * 4, stream);
    hipMemsetAsync(poolY, 0, (size_t)GMAX * DDIM * 4, stream);

    k_p1<<<NPB, 256, 0, stream>>>(dst, batch, deg, blockHist, g8, E, M);
    k_scanB<<<1, 256, 0, stream>>>(blockHist, blockBase, gStart);
    k_pack<<<(N + 255) / 256, 256, 0, stream>>>(deg, node_ids, nd, N);
    k_partbin<<<NPB, 256, 0, stream>>>(src, dst, g8, nd, blockBase, parts, C, E, M);

    k_t1<<<17, DDIM, 0, stream>>>(emb, W1, t1);
    k_x1<<<(N + 3) / 4, 256, 0, stream>>>(nd, C, t1, b1, x1u, N);
    k_conv2g<<<GMAX * SLICES, 256, 0, stream>>>(parts, gStart, x1u, poolY);
    k_out<<<GMAX, 128, 0, stream>>>(poolY, batch, W2, b2, out, N);
}

// Round 9
// 369.890 us; speedup vs baseline: 3.8308x; 1.0289x over previous
//
#include <hip/hip_runtime.h>
#include <hip/hip_bf16.h>

// GCN: x=emb[ids]; x1=relu(GCNConv(x,W1,b1)); y=Ahat@x1; out[g]=b2+(mean_g y)@W2
//
// Structure (R9):
//  - conv1: rank-17 input -> t1=(emb@W1); per-node 17 type bins C (edge atomics)
//    then dense 17-term FMA -> x1 (bf16x2, lane holds feats {lane, lane+64}).
//  - conv2+pool edge-parallel: items (E edges + N self loops) partitioned BY
//    GRAPH, per-graph blocks accumulate in REGISTERS (R6: correlated-address
//    LDS atomic RMW serializes; registers don't).
//  - R8: bin fused into partition pass; g8[item]=batch[dst] cached by p1.
//  - R9: NPB 512->2048 (p1/partbin were 19% occupancy, latency-bound on
//    random nd gathers with only 8 waves/CU); serial k_scanB replaced by
//    parallel per-graph scan (k_scanG 64 blocks + tiny k_scanT).

#define DDIM 128
#define CPAD 20      // C row stride (17 used; 80 B keeps float4 alignment)
#define GMAX 64
#define NPB  2048    // partition blocks (fixed item ranges); 8 blocks/CU
#define SLICES 32    // conv2 blocks per graph
typedef unsigned int uint;
typedef unsigned char uchar;

__device__ __forceinline__ float bflo(uint v) { return __uint_as_float(v << 16); }
__device__ __forceinline__ float bfhi(uint v) { return __uint_as_float(v & 0xffff0000u); }
__device__ __forceinline__ uint packbf(float x, float y) {  // RNE round both
    uint ux = __float_as_uint(x), uy = __float_as_uint(y);
    ux = (ux + 0x7fff + ((ux >> 16) & 1)) >> 16;
    uy = (uy + 0x7fff + ((uy >> 16) & 1)) & 0xffff0000u;
    return ux | uy;
}

// Pass 1: deg atomics + per-block per-graph histogram + g8 cache.
__global__ void __launch_bounds__(256) k_p1(
        const int* __restrict__ dst, const int* __restrict__ batch,
        int* __restrict__ deg, int* __restrict__ blockHist,
        uchar* __restrict__ g8, int E, int M) {
    __shared__ int h[4][GMAX];
    int t = threadIdx.x, wave = t >> 6;
    if ((t & 63) < GMAX) h[wave][t & 63] = 0;
    __syncthreads();
    int per = (M + NPB - 1) / NPB;
    int lo = blockIdx.x * per;
    int hi = lo + per; if (hi > M) hi = M;
    for (int cb = lo; cb < hi; cb += 1024) {
        int idx_[4]; bool v_[4], isE_[4];
#pragma unroll
        for (int q = 0; q < 4; q++) {
            int item = cb + q * 256 + t;
            v_[q] = item < hi;
            isE_[q] = item < E;
            idx_[q] = 0;
            if (v_[q]) idx_[q] = isE_[q] ? dst[item] : (item - E);
        }
#pragma unroll
        for (int q = 0; q < 4; q++) {
            if (v_[q]) {
                int g = batch[idx_[q]];              // 4 gathers in flight
                g8[cb + q * 256 + t] = (uchar)g;
                if (isE_[q]) atomicAdd(&deg[idx_[q]], 1);
                atomicAdd(&h[wave][g], 1);
            }
        }
    }
    __syncthreads();
    if (t < GMAX)
        blockHist[blockIdx.x * GMAX + t] = h[0][t] + h[1][t] + h[2][t] + h[3][t];
}

// Per-graph parallel exclusive scan over NPB block histograms.
// Block g: localBase[b][g] = sum_{b'<b} blockHist[b'][g]; tot[g] = column sum.
__global__ void __launch_bounds__(256) k_scanG(
        const int* __restrict__ blockHist, int* __restrict__ localBase,
        int* __restrict__ tot) {
    __shared__ int sm[256];
    int g = blockIdx.x, t = threadIdx.x;
    const int PER = NPB / 256;     // 8
    int v[PER], loc[PER];
    int run = 0;
#pragma unroll
    for (int q = 0; q < PER; q++) {
        v[q] = blockHist[(t * PER + q) * GMAX + g];
        loc[q] = run;
        run += v[q];
    }
    sm[t] = run; __syncthreads();
    for (int off = 1; off < 256; off <<= 1) {
        int a = (t >= off) ? sm[t - off] : 0;
        __syncthreads();
        sm[t] += a; __syncthreads();
    }
    int excl = sm[t] - run;
#pragma unroll
    for (int q = 0; q < PER; q++)
        localBase[(t * PER + q) * GMAX + g] = excl + loc[q];
    if (t == 255) tot[g] = sm[255];
}

// gStart[65] from tot (tiny)
__global__ void k_scanT(const int* __restrict__ tot, int* __restrict__ gStart) {
    if (threadIdx.x == 0) {
        int run = 0;
        for (int g = 0; g < GMAX; g++) { gStart[g] = run; run += tot[g]; }
        gStart[GMAX] = run;
    }
}

// nd[i] = {dinv_i, type_i bits}
__global__ void k_pack(const int* __restrict__ deg, const int* __restrict__ ids,
                       float2* __restrict__ nd, int N) {
    int i = blockIdx.x * blockDim.x + threadIdx.x;
    if (i < N) {
        float dinv = rsqrtf((float)(deg[i] + 1));
        nd[i] = make_float2(dinv, __int_as_float(ids[i]));
    }
}

// Pass 2 (fused): partition items into parts[]={src bits, w} by graph
// AND accumulate conv1 type bins C[d][type_s] += dinv_s for real edges.
__global__ void __launch_bounds__(256) k_partbin(
        const int* __restrict__ src, const int* __restrict__ dst,
        const uchar* __restrict__ g8, const float2* __restrict__ nd,
        const int* __restrict__ localBase, const int* __restrict__ gStart,
        float2* __restrict__ parts, float* __restrict__ C, int E, int M) {
    __shared__ int rk[GMAX];
    __shared__ int base[GMAX];
    int t = threadIdx.x, b = blockIdx.x;
    if (t < GMAX) base[t] = gStart[t] + localBase[b * GMAX + t];
    int per = (M + NPB - 1) / NPB;
    int lo = b * per;
    int hi = lo + per; if (hi > M) hi = M;
    for (int cb = lo; cb < hi; cb += 1024) {
        if (t < GMAX) rk[t] = 0;
        __syncthreads();
        int s_[4], g_[4], r_[4], d_[4]; float w_[4]; bool v_[4], isE_[4];
#pragma unroll
        for (int q = 0; q < 4; q++) {            // batched independent loads
            int item = cb + q * 256 + t;
            v_[q] = item < hi;
            isE_[q] = item < E;
            s_[q] = 0; d_[q] = 0; g_[q] = 0; r_[q] = 0; w_[q] = 0.f;
            if (v_[q]) {
                g_[q] = g8[item];
                if (isE_[q]) { s_[q] = src[item]; d_[q] = dst[item]; }
                else         { s_[q] = item - E;  d_[q] = item - E; }
            }
        }
#pragma unroll
        for (int q = 0; q < 4; q++) {            // gathers 8-wide in flight
            if (v_[q]) {
                float2 ns = nd[s_[q]];
                float dd = nd[d_[q]].x;
                w_[q] = ns.x * dd;
                if (isE_[q])                     // conv1 bin (fire-and-forget)
                    atomicAdd(&C[d_[q] * CPAD + __float_as_int(ns.y)], ns.x);
                r_[q] = atomicAdd(&rk[g_[q]], 1);
            }
        }
        __syncthreads();
#pragma unroll
        for (int q = 0; q < 4; q++)
            if (v_[q]) parts[base[g_[q]] + r_[q]] =
                make_float2(__int_as_float(s_[q]), w_[q]);
        __syncthreads();
        if (t < GMAX) base[t] += rk[t];
        __syncthreads();
    }
}

// t1 = emb @ W1  (17 x 128)
__global__ void k_t1(const float* __restrict__ emb, const float* __restrict__ W1,
                     float* __restrict__ t1) {
    int t = blockIdx.x, f = threadIdx.x;
    float acc = 0.f;
    for (int k = 0; k < DDIM; k++) acc += emb[t * DDIM + k] * W1[k * DDIM + f];
    t1[t * DDIM + f] = acc;
}

// x1[i] = relu(b1 + dinv_i*(sum_t C[i][t]*t1[t] + dinv_i*t1[ti]))  -> bf16x2
__global__ void __launch_bounds__(256) k_x1(
        const float2* __restrict__ nd, const float* __restrict__ C,
        const float* __restrict__ t1, const float* __restrict__ b1,
        uint* __restrict__ x1u, int N) {
    int lane = threadIdx.x & 63, wave = threadIdx.x >> 6;
    int i = blockIdx.x * 4 + wave;
    if (i >= N) return;
    float2 ndi = nd[i];
    float dinv_i = ndi.x;
    int ti = __float_as_int(ndi.y);
    const float4* Cv = (const float4*)(C + i * CPAD);
    float4 c0 = Cv[0], c1 = Cv[1], c2 = Cv[2], c3 = Cv[3];
    float c16 = C[i * CPAD + 16];
    float cc[17] = {c0.x, c0.y, c0.z, c0.w, c1.x, c1.y, c1.z, c1.w,
                    c2.x, c2.y, c2.z, c2.w, c3.x, c3.y, c3.z, c3.w, c16};
    float ax = dinv_i * t1[ti * DDIM + lane];
    float ay = dinv_i * t1[ti * DDIM + 64 + lane];
#pragma unroll
    for (int t = 0; t < 17; t++) {
        ax += cc[t] * t1[t * DDIM + lane];
        ay += cc[t] * t1[t * DDIM + 64 + lane];
    }
    float vx = b1[lane]      + dinv_i * ax;
    float vy = b1[64 + lane] + dinv_i * ay;
    vx = vx > 0.f ? vx : 0.f;
    vy = vy > 0.f ? vy : 0.f;
    x1u[i * 64 + lane] = packbf(vx, vy);
}

// conv2+pool: block owns one (graph, slice); register accumulation; 8-wide gathers.
__global__ void __launch_bounds__(256) k_conv2g(
        const float2* __restrict__ parts, const int* __restrict__ gStart,
        const uint* __restrict__ x1u, float* __restrict__ poolY) {
    __shared__ float2 meta[4][64];
    __shared__ float red[4][DDIM];
    int t = threadIdx.x, lane = t & 63, wave = t >> 6;
    int g = blockIdx.x / SLICES, sl = blockIdx.x % SLICES;
    int a = gStart[g], bnd = gStart[g + 1];
    long long len = bnd - a;
    int s0 = a + (int)(len * sl / SLICES);
    int s1 = a + (int)(len * (sl + 1) / SLICES);
    float ax = 0.f, ay = 0.f;
    for (int cb = s0 + wave * 64; cb < s1; cb += 4 * 64) {
        int idx = cb + lane;
        float2 m = (idx < s1) ? parts[idx] : make_float2(__int_as_float(0), 0.f);
        meta[wave][lane] = m;   // within-wave LDS write->read (lgkm ordered)
#pragma unroll
        for (int jj = 0; jj < 64; jj += 8) {
            float2 m0 = meta[wave][jj + 0], m1 = meta[wave][jj + 1];
            float2 m2 = meta[wave][jj + 2], m3 = meta[wave][jj + 3];
            float2 m4 = meta[wave][jj + 4], m5 = meta[wave][jj + 5];
            float2 m6 = meta[wave][jj + 6], m7 = meta[wave][jj + 7];
            uint v0 = x1u[__float_as_int(m0.x) * 64 + lane];
            uint v1 = x1u[__float_as_int(m1.x) * 64 + lane];
            uint v2 = x1u[__float_as_int(m2.x) * 64 + lane];
            uint v3 = x1u[__float_as_int(m3.x) * 64 + lane];
            uint v4 = x1u[__float_as_int(m4.x) * 64 + lane];
            uint v5 = x1u[__float_as_int(m5.x) * 64 + lane];
            uint v6 = x1u[__float_as_int(m6.x) * 64 + lane];
            uint v7 = x1u[__float_as_int(m7.x) * 64 + lane];
            ax += m0.y * bflo(v0) + m1.y * bflo(v1) + m2.y * bflo(v2) + m3.y * bflo(v3)
                + m4.y * bflo(v4) + m5.y * bflo(v5) + m6.y * bflo(v6) + m7.y * bflo(v7);
            ay += m0.y * bfhi(v0) + m1.y * bfhi(v1) + m2.y * bfhi(v2) + m3.y * bfhi(v3)
                + m4.y * bfhi(v4) + m5.y * bfhi(v5) + m6.y * bfhi(v6) + m7.y * bfhi(v7);
        }
    }
    red[wave][lane] = ax;
    red[wave][64 + lane] = ay;
    __syncthreads();
    if (wave == 0) {
        float vx = red[0][lane] + red[1][lane] + red[2][lane] + red[3][lane];
        float vy = red[0][64 + lane] + red[1][64 + lane] + red[2][64 + lane] + red[3][64 + lane];
        atomicAdd(&poolY[g * DDIM + lane], vx);
        atomicAdd(&poolY[g * DDIM + 64 + lane], vy);
    }
}

// out[g] = b2 + (poolY[g]/cnt[g]) @ W2 ; cnt via binary search on sorted batch
__global__ void __launch_bounds__(128) k_out(
        const float* __restrict__ poolY, const int* __restrict__ batch,
        const float* __restrict__ W2, const float* __restrict__ b2,
        float* __restrict__ out, int N) {
    __shared__ float py[DDIM];
    __shared__ int cs;
    int g = blockIdx.x, f = threadIdx.x;
    py[f] = poolY[g * DDIM + f];
    if (f == 0) {
        auto lb = [&](int key) {
            int lo = 0, hi = N;
            while (lo < hi) {
                int mid = (lo + hi) >> 1;
                if (batch[mid] < key) lo = mid + 1; else hi = mid;
            }
            return lo;
        };
        cs = lb(g + 1) - lb(g);
    }
    __syncthreads();
    float acc = 0.f;
    for (int k = 0; k < DDIM; k++) acc += py[k] * W2[k * DDIM + f];
    int c = cs;
    out[g * DDIM + f] = (c > 0) ? (b2[f] + acc / (float)c) : 0.f;
}

extern "C" void kernel_launch(void* const* d_in, const int* in_sizes, int n_in,
                              void* d_out, int out_size, void* d_ws, size_t ws_size,
                              hipStream_t stream) {
    const int* node_ids = (const int*)d_in[0];
    const int* edge_index = (const int*)d_in[1];
    const int* batch = (const int*)d_in[2];
    const float* emb = (const float*)d_in[4];
    const float* W1 = (const float*)d_in[5];
    const float* b1 = (const float*)d_in[6];
    const float* W2 = (const float*)d_in[7];
    const float* b2 = (const float*)d_in[8];
    float* out = (float*)d_out;

    const int N = in_sizes[0];
    const int E = in_sizes[1] / 2;
    const int M = E + N;
    const int* src = edge_index;
    const int* dst = edge_index + E;

    char* ws = (char*)d_ws;
    size_t off = 0;
    auto carve = [&](size_t bytes) { char* p = ws + off; off = (off + bytes + 255) & ~size_t(255); return p; };
    uint*   x1u       = (uint*)carve((size_t)N * 64 * 4);     // bf16x2 packed
    float2* parts     = (float2*)carve((size_t)M * 8);        // {src bits, w} by graph
    float*  C         = (float*)carve((size_t)N * CPAD * 4);  // type bins
    float2* nd        = (float2*)carve((size_t)N * 8);
    int*    deg       = (int*)carve((size_t)N * 4);
    uchar*  g8        = (uchar*)carve((size_t)M);             // cached batch[dst]
    int*    blockHist = (int*)carve((size_t)NPB * GMAX * 4);
    int*    localBase = (int*)carve((size_t)NPB * GMAX * 4);
    int*    tot       = (int*)carve(GMAX * 4);
    int*    gStart    = (int*)carve((GMAX + 1) * 4);
    float*  t1        = (float*)carve(17 * DDIM * 4);
    float*  poolY     = (float*)carve((size_t)GMAX * DDIM * 4);

    hipMemsetAsync(deg,   0, (size_t)N * 4, stream);
    hipMemsetAsync(C,     0, (size_t)N * CPAD * 4, stream);
    hipMemsetAsync(poolY, 0, (size_t)GMAX * DDIM * 4, stream);

    k_p1<<<NPB, 256, 0, stream>>>(dst, batch, deg, blockHist, g8, E, M);
    k_scanG<<<GMAX, 256, 0, stream>>>(blockHist, localBase, tot);
    k_scanT<<<1, 64, 0, stream>>>(tot, gStart);
    k_pack<<<(N + 255) / 256, 256, 0, stream>>>(deg, node_ids, nd, N);
    k_partbin<<<NPB, 256, 0, stream>>>(src, dst, g8, nd, localBase, gStart, parts, C, E, M);

    k_t1<<<17, DDIM, 0, stream>>>(emb, W1, t1);
    k_x1<<<(N + 3) / 4, 256, 0, stream>>>(nd, C, t1, b1, x1u, N);
    k_conv2g<<<GMAX * SLICES, 256, 0, stream>>>(parts, gStart, x1u, poolY);
    k_out<<<GMAX, 128, 0, stream>>>(poolY, batch, W2, b2, out, N);
}